// Round 11
// baseline (169.983 us; speedup 1.0000x reference)
//
#include <hip/hip_runtime.h>

#define NB 16
#define NQ 64
#define NK 1024
#define ES 256
#define NH 128
#define VS 256
#define KT 16                       // pv k-splits (64 keys each)
#define SCALE2 2.885390081777927f   // 2*log2(e)
#define L2E    1.4426950408889634f  // log2(e)

__device__ __forceinline__ float exp2_fast(float x) {
    float r; asm("v_exp_f32 %0, %1" : "=v"(r) : "v"(x)); return r;
}
__device__ __forceinline__ float rcp_fast(float x) {
    float r; asm("v_rcp_f32 %0, %1" : "=v"(r) : "v"(x)); return r;
}
__device__ __forceinline__ void fma4(float4& acc, const float4& wv, float s) {
    acc.x = fmaf(wv.x, s, acc.x);
    acc.y = fmaf(wv.y, s, acc.y);
    acc.z = fmaf(wv.z, s, acc.z);
    acc.w = fmaf(wv.w, s, acc.w);
}

// ---------------------------------------------------------------
// K1: projections, pre-scaled by 2*log2(e).
// R10 fix: 16 rows/block -> 1088 blocks (~4.25/CU) so W-load latency
// is hidden by TLP (was 544 blocks, 19% occupancy, VALUBusy 17%).
// Thread = (h4 col-group, g) -> rows g, g+8. LDS reads 2-way = free.
// ---------------------------------------------------------------
__global__ __launch_bounds__(256) void proj_kernel(
    const float* __restrict__ queries, const float* __restrict__ keys,
    const float* __restrict__ Wq, const float* __restrict__ Wk,
    float* __restrict__ qp, float* __restrict__ kp)
{
    __shared__ __align__(16) float x_lds[16 * 256];
    const int bi  = blockIdx.x;
    const int tid = threadIdx.x;

    const float* src; const float* W; float* dst;
    if (bi < 64) {                      // query rows: 64 blocks * 16 = 1024
        src = queries + (size_t)bi * 16 * ES;
        W   = Wq;
        dst = qp + (size_t)bi * 16 * NH;
    } else {                            // key rows: 1024 blocks * 16 = 16384
        const int r0 = (bi - 64) * 16;
        src = keys + (size_t)r0 * ES;
        W   = Wk;
        dst = kp + (size_t)r0 * NH;
    }

    // stage 16 rows x 256 f32 into LDS (1024 float4)
    const float4* s4 = (const float4*)src;
    float4* x4 = (float4*)x_lds;
#pragma unroll
    for (int i = 0; i < 4; ++i) x4[tid + i * 256] = s4[tid + i * 256];
    __syncthreads();

    const int h4 = tid & 31;   // 4 output cols
    const int g  = tid >> 5;   // rows g, g+8
    const float* xa = x_lds + (g + 0) * 256;
    const float* xb = x_lds + (g + 8) * 256;

    float4 a0 = {0,0,0,0}, a1 = {0,0,0,0};
#pragma unroll 4
    for (int e = 0; e < 256; e += 4) {
        const float4 va = *(const float4*)(xa + e);
        const float4 vb = *(const float4*)(xb + e);
#pragma unroll
        for (int j = 0; j < 4; ++j) {
            const float4 w4 = *(const float4*)(W + (size_t)(e + j) * NH + h4 * 4);
            const float fa = (j==0)?va.x:(j==1)?va.y:(j==2)?va.z:va.w;
            const float fb = (j==0)?vb.x:(j==1)?vb.y:(j==2)?vb.z:vb.w;
            fma4(a0, w4, fa);
            fma4(a1, w4, fb);
        }
    }
    const float c = SCALE2;
    float4 o;
    o.x=a0.x*c; o.y=a0.y*c; o.z=a0.z*c; o.w=a0.w*c;
    *(float4*)(dst + (size_t)(g + 0) * NH + h4 * 4) = o;
    o.x=a1.x*c; o.y=a1.y*c; o.z=a1.z*c; o.w=a1.w*c;
    *(float4*)(dst + (size_t)(g + 8) * NH + h4 * 4) = o;
}

// ---------------------------------------------------------------
// K2: pT[b,k,q] = exp(scores) (masked -> 0), transposed layout.
// 4-way sigmoid combine: 5 trans + 14 VALU per 4 elems.
// Early-exit for fully-masked 64-key tiles (~22% of blocks).
// ---------------------------------------------------------------
__global__ __launch_bounds__(256, 4) void scores_kernel(
    const float* __restrict__ qp, const float* __restrict__ kp,
    const float* __restrict__ Ws, const int* __restrict__ valid_len,
    float* __restrict__ pT)
{
    __shared__ __align__(16) float kp_s[64 * 128];
    __shared__ __align__(16) float qp_s[8 * 128];
    __shared__ __align__(16) float ws_s[128];

    const int kt  = blockIdx.x;   // 0..15
    const int qt  = blockIdx.y;   // 0..7
    const int b   = blockIdx.z;   // 0..15
    const int tid = threadIdx.x;
    const int lane = tid & 63;
    const int w    = tid >> 6;
    const int kg   = kt * 64 + lane;
    const int vl   = valid_len[b];

    if (kt * 64 + 63 < vl) {      // whole tile masked
        pT[((size_t)b * NK + kg) * NQ + qt * 8 + w]     = 0.0f;
        pT[((size_t)b * NK + kg) * NQ + qt * 8 + w + 4] = 0.0f;
        return;
    }

    // stage kp tile: 64 rows x 128 cols = 2048 float4, swizzled
    const float4* ksrc = (const float4*)(kp + (size_t)(b * NK + kt * 64) * NH);
#pragma unroll
    for (int i = 0; i < 8; ++i) {
        const int idx = tid + i * 256;          // 0..2047
        const int row = idx >> 5, c = idx & 31;
        const float4 v = ksrc[idx];
        *(float4*)(kp_s + row * 128 + 4 * (c ^ (row & 7))) = v;
    }
    ((float4*)qp_s)[tid & 255] = ((const float4*)(qp + (size_t)(b * NQ + qt * 8) * NH))[tid & 255];
    if (tid < 32) {
        float4 t = ((const float4*)Ws)[tid];
        t.x *= -2.f; t.y *= -2.f; t.z *= -2.f; t.w *= -2.f;
        ((float4*)ws_s)[tid] = t;
    }
    __syncthreads();

    // sumWs via butterfly (ws_s holds -2*ws)
    float sw = ws_s[lane] + ws_s[lane + 64];
#pragma unroll
    for (int off = 32; off; off >>= 1) sw += __shfl_xor(sw, off);
    const float sW = -0.5f * sw;

    const float* qa = qp_s + w * 128;
    const float* qb = qp_s + (w + 4) * 128;
    const float* kr = kp_s + lane * 128;
    const int sw_x = lane & 7;

    float s0 = 0.f, s1 = 0.f;
#pragma unroll 4
    for (int c = 0; c < 32; ++c) {
        const float4 kv = *(const float4*)(kr + 4 * (c ^ sw_x));
        const float4 va = *(const float4*)(qa + 4 * c);
        const float4 vb = *(const float4*)(qb + 4 * c);
        const float4 wv = *(const float4*)(ws_s + 4 * c);
        {   // row a: 4 exp2 + 1 rcp
            const float u0 = 1.0f + exp2_fast(va.x + kv.x);
            const float u1 = 1.0f + exp2_fast(va.y + kv.y);
            const float u2 = 1.0f + exp2_fast(va.z + kv.z);
            const float u3 = 1.0f + exp2_fast(va.w + kv.w);
            const float d01 = u0 * u1, d23 = u2 * u3;
            const float n01 = fmaf(wv.y, u0, wv.x * u1);
            const float n23 = fmaf(wv.w, u2, wv.z * u3);
            const float n   = fmaf(n23, d01, n01 * d23);
            s0 = fmaf(n, rcp_fast(d01 * d23), s0);
        }
        {   // row b
            const float u0 = 1.0f + exp2_fast(vb.x + kv.x);
            const float u1 = 1.0f + exp2_fast(vb.y + kv.y);
            const float u2 = 1.0f + exp2_fast(vb.z + kv.z);
            const float u3 = 1.0f + exp2_fast(vb.w + kv.w);
            const float d01 = u0 * u1, d23 = u2 * u3;
            const float n01 = fmaf(wv.y, u0, wv.x * u1);
            const float n23 = fmaf(wv.w, u2, wv.z * u3);
            const float n   = fmaf(n23, d01, n01 * d23);
            s1 = fmaf(n, rcp_fast(d01 * d23), s1);
        }
    }

    const float p0 = (kg >= vl) ? exp2_fast((sW + s0) * L2E) : 0.0f;
    const float p1 = (kg >= vl) ? exp2_fast((sW + s1) * L2E) : 0.0f;
    pT[((size_t)b * NK + kg) * NQ + qt * 8 + w]     = p0;
    pT[((size_t)b * NK + kg) * NQ + qt * 8 + w + 4] = p1;
}

// ---------------------------------------------------------------
// K3: partial PV + partial z. R10 fix: 64-key tiles -> grid 512
// (was 256 = 1 block/CU, latency-bound). Early-exit ~22% of tiles.
// ---------------------------------------------------------------
__global__ __launch_bounds__(256) void pv_kernel(
    const float* __restrict__ pT, const float* __restrict__ values,
    const int* __restrict__ valid_len,
    float* __restrict__ part, float* __restrict__ zpart)
{
    __shared__ __align__(16) float a_s[64][36];
    __shared__ float zp_s[4][32];
    const int kt  = blockIdx.x;   // 0..15
    const int qh  = blockIdx.y;   // 0..1
    const int b   = blockIdx.z;   // 0..15
    const int tid = threadIdx.x;

    const int vl = valid_len[b];
    if (kt * 64 + 63 < vl) {      // whole tile masked -> partials zero
        if (tid < 32) zpart[((size_t)kt * NB + b) * NQ + qh * 32 + tid] = 0.f;
#pragma unroll
        for (int q = 0; q < 32; ++q)
            part[(((size_t)kt * NB + b) * NQ + qh * 32 + q) * VS + tid] = 0.f;
        return;
    }

    // stage a-tile: 64 k x 32 q (512 float4, 2 per thread)
    {
        const int q4 = (tid & 7) * 4;
        const int k0 = tid >> 3;          // 0..31
#pragma unroll
        for (int i = 0; i < 2; ++i) {
            const int k = k0 + 32 * i;
            const float4 v = *(const float4*)(
                pT + ((size_t)b * NK + kt * 64 + k) * NQ + qh * 32 + q4);
            *(float4*)(&a_s[k][q4]) = v;
        }
    }
    __syncthreads();

    // partial z: wave w sums k in [16w, 16w+16), q' = lane&31
    {
        const int lane = tid & 63;
        const int w    = tid >> 6;
        const int qq   = lane & 31;
        float z = 0.f;
#pragma unroll
        for (int i = 0; i < 16; ++i) z += a_s[w * 16 + i][qq];
        if (lane < 32) zp_s[w][qq] = z;
    }
    __syncthreads();
    if (tid < 32) {
        const float zf = zp_s[0][tid] + zp_s[1][tid] + zp_s[2][tid] + zp_s[3][tid];
        zpart[((size_t)kt * NB + b) * NQ + qh * 32 + tid] = zf;
    }

    // main: thread = vcol, 32 q accumulators, 64-k loop
    float acc[32];
#pragma unroll
    for (int i = 0; i < 32; ++i) acc[i] = 0.f;

    const float* vb = values + ((size_t)b * NK + kt * 64) * VS + tid;
#pragma unroll 4
    for (int k = 0; k < 64; ++k) {
        const float v = vb[(size_t)k * VS];
#pragma unroll
        for (int j = 0; j < 8; ++j) {
            const float4 a = *(const float4*)(&a_s[k][4 * j]);
            acc[4*j+0] = fmaf(a.x, v, acc[4*j+0]);
            acc[4*j+1] = fmaf(a.y, v, acc[4*j+1]);
            acc[4*j+2] = fmaf(a.z, v, acc[4*j+2]);
            acc[4*j+3] = fmaf(a.w, v, acc[4*j+3]);
        }
    }
#pragma unroll
    for (int q = 0; q < 32; ++q)
        part[(((size_t)kt * NB + b) * NQ + qh * 32 + q) * VS + tid] = acc[q];
}

// ---------------------------------------------------------------
// K4: out = (sum_kt part) / (sum_kt zpart). One block per (b,q) row.
// ---------------------------------------------------------------
__global__ __launch_bounds__(256) void finish_kernel(
    const float* __restrict__ part, const float* __restrict__ zpart,
    float* __restrict__ out)
{
    const int r   = blockIdx.x;   // b*64+q
    const int tid = threadIdx.x;
    const int b = r >> 6, q = r & 63;
    float z = 0.f, s = 0.f;
#pragma unroll
    for (int kt = 0; kt < KT; ++kt) {
        z += zpart[((size_t)kt * NB + b) * NQ + q];
        s += part[(((size_t)kt * NB + b) * NQ + q) * VS + tid];
    }
    out[(size_t)r * VS + tid] = s / z;
}

// ---------------------------------------------------------------
extern "C" void kernel_launch(void* const* d_in, const int* in_sizes, int n_in,
                              void* d_out, int out_size, void* d_ws, size_t ws_size,
                              hipStream_t stream)
{
    (void)in_sizes; (void)n_in; (void)out_size; (void)ws_size;
    const float* queries = (const float*)d_in[0];
    const float* keys    = (const float*)d_in[1];
    const float* values  = (const float*)d_in[2];
    const int*   vlen    = (const int*)d_in[3];
    const float* Wq      = (const float*)d_in[4];
    const float* Wk      = (const float*)d_in[5];
    const float* Ws      = (const float*)d_in[6];
    float* out = (float*)d_out;

    // workspace layout (floats), no overlays: ~30 MB total
    float* qp    = (float*)d_ws;           // 131072
    float* kp    = qp + 131072;            // 2097152
    float* pT    = kp + 2097152;           // 1048576
    float* zpart = pT + 1048576;           // 16384 (KT*NB*NQ)
    float* part  = zpart + 16384;          // 4194304 (KT*NB*NQ*VS)

    proj_kernel<<<1088, 256, 0, stream>>>(queries, keys, Wq, Wk, qp, kp);
    scores_kernel<<<dim3(16, 8, 16), 256, 0, stream>>>(qp, kp, Ws, vlen, pT);
    pv_kernel<<<dim3(KT, 2, 16), 256, 0, stream>>>(pT, values, vlen, part, zpart);
    finish_kernel<<<1024, 256, 0, stream>>>(part, zpart, out);
}

// Round 12
// 154.621 us; speedup vs baseline: 1.0993x; 1.0993x over previous
//
#include <hip/hip_runtime.h>

#define NB 16
#define NQ 64
#define NK 1024
#define ES 256
#define NH 128
#define VS 256
#define KT 16                       // pv k-splits (64 keys each)
#define SCALE2 2.885390081777927f   // 2*log2(e)
#define L2E    1.4426950408889634f  // log2(e)

__device__ __forceinline__ float exp2_fast(float x) {
    float r; asm("v_exp_f32 %0, %1" : "=v"(r) : "v"(x)); return r;
}
__device__ __forceinline__ float rcp_fast(float x) {
    float r; asm("v_rcp_f32 %0, %1" : "=v"(r) : "v"(x)); return r;
}
__device__ __forceinline__ void fma4(float4& acc, const float4& wv, float s) {
    acc.x = fmaf(wv.x, s, acc.x);
    acc.y = fmaf(wv.y, s, acc.y);
    acc.z = fmaf(wv.z, s, acc.z);
    acc.w = fmaf(wv.w, s, acc.w);
}

// ---------------------------------------------------------------
// K1: projections, pre-scaled by 2*log2(e).
// R11 post-mortem: VGPR=32 strangled ILP (VALUBusy 17% = pure L2-load
// latency). Fix: 4 rows/thread (more FMA per W-load), launch_bounds
// (256,2) to lift VGPR cap, explicit ping-pong W prefetch (wa/wb +
// prefetch-next issued BEFORE the FMA block) -> ~8 loads in flight.
// ---------------------------------------------------------------
__global__ __launch_bounds__(256, 2) void proj_kernel(
    const float* __restrict__ queries, const float* __restrict__ keys,
    const float* __restrict__ Wq, const float* __restrict__ Wk,
    float* __restrict__ qp, float* __restrict__ kp)
{
    __shared__ __align__(16) float x_lds[32 * 256];
    const int bi  = blockIdx.x;
    const int tid = threadIdx.x;

    const float* src; const float* W; float* dst;
    if (bi < 32) {                      // query rows: 32 blocks * 32 = 1024
        src = queries + (size_t)bi * 32 * ES;
        W   = Wq;
        dst = qp + (size_t)bi * 32 * NH;
    } else {                            // key rows: 512 blocks * 32 = 16384
        const int r0 = (bi - 32) * 32;
        src = keys + (size_t)r0 * ES;
        W   = Wk;
        dst = kp + (size_t)r0 * NH;
    }

    // stage 32 rows x 256 f32 into LDS
    const float4* s4 = (const float4*)src;
    float4* x4 = (float4*)x_lds;
#pragma unroll
    for (int i = 0; i < 8; ++i) x4[tid + i * 256] = s4[tid + i * 256];
    __syncthreads();

    const int h4 = tid & 31;   // 4 output cols
    const int g  = tid >> 5;   // rows g, g+8, g+16, g+24
    const float* x0 = x_lds + (g +  0) * 256;
    const float* x1 = x_lds + (g +  8) * 256;
    const float* x2 = x_lds + (g + 16) * 256;
    const float* x3 = x_lds + (g + 24) * 256;
    const float* Wc = W + h4 * 4;       // column base

    float4 a0 = {0,0,0,0}, a1 = {0,0,0,0}, a2 = {0,0,0,0}, a3 = {0,0,0,0};

    // prefetch pipeline: wa holds W rows e..e+3, wb holds e+4..e+7
    float4 wa0, wa1, wa2, wa3, wb0, wb1, wb2, wb3;
    wa0 = *(const float4*)(Wc + (size_t)0 * NH);
    wa1 = *(const float4*)(Wc + (size_t)1 * NH);
    wa2 = *(const float4*)(Wc + (size_t)2 * NH);
    wa3 = *(const float4*)(Wc + (size_t)3 * NH);
    wb0 = *(const float4*)(Wc + (size_t)4 * NH);
    wb1 = *(const float4*)(Wc + (size_t)5 * NH);
    wb2 = *(const float4*)(Wc + (size_t)6 * NH);
    wb3 = *(const float4*)(Wc + (size_t)7 * NH);

#define PROJ_PHASE(WREG0, WREG1, WREG2, WREG3, EOFF)                         \
    {                                                                        \
        const float4 va = *(const float4*)(x0 + (EOFF));                     \
        const float4 vb = *(const float4*)(x1 + (EOFF));                     \
        const float4 vc = *(const float4*)(x2 + (EOFF));                     \
        const float4 vd = *(const float4*)(x3 + (EOFF));                     \
        fma4(a0, WREG0, va.x); fma4(a1, WREG0, vb.x);                        \
        fma4(a2, WREG0, vc.x); fma4(a3, WREG0, vd.x);                        \
        fma4(a0, WREG1, va.y); fma4(a1, WREG1, vb.y);                        \
        fma4(a2, WREG1, vc.y); fma4(a3, WREG1, vd.y);                        \
        fma4(a0, WREG2, va.z); fma4(a1, WREG2, vb.z);                        \
        fma4(a2, WREG2, vc.z); fma4(a3, WREG2, vd.z);                        \
        fma4(a0, WREG3, va.w); fma4(a1, WREG3, vb.w);                        \
        fma4(a2, WREG3, vc.w); fma4(a3, WREG3, vd.w);                        \
    }

#pragma unroll 1
    for (int e = 0; e < 240; e += 8) {
        // phase A: prefetch rows e+8..e+11, compute with wa
        float4 t0 = *(const float4*)(Wc + (size_t)(e +  8) * NH);
        float4 t1 = *(const float4*)(Wc + (size_t)(e +  9) * NH);
        float4 t2 = *(const float4*)(Wc + (size_t)(e + 10) * NH);
        float4 t3 = *(const float4*)(Wc + (size_t)(e + 11) * NH);
        PROJ_PHASE(wa0, wa1, wa2, wa3, e);
        wa0 = t0; wa1 = t1; wa2 = t2; wa3 = t3;
        // phase B: prefetch rows e+12..e+15, compute with wb
        t0 = *(const float4*)(Wc + (size_t)(e + 12) * NH);
        t1 = *(const float4*)(Wc + (size_t)(e + 13) * NH);
        t2 = *(const float4*)(Wc + (size_t)(e + 14) * NH);
        t3 = *(const float4*)(Wc + (size_t)(e + 15) * NH);
        PROJ_PHASE(wb0, wb1, wb2, wb3, e + 4);
        wb0 = t0; wb1 = t1; wb2 = t2; wb3 = t3;
    }
    // epilogue: e = 240..247 (wa holds 240-243, wb holds 244-247)
    PROJ_PHASE(wa0, wa1, wa2, wa3, 240);
    PROJ_PHASE(wb0, wb1, wb2, wb3, 244);
    // last 8 rows 248..255: direct loads
    {
        float4 t0 = *(const float4*)(Wc + (size_t)248 * NH);
        float4 t1 = *(const float4*)(Wc + (size_t)249 * NH);
        float4 t2 = *(const float4*)(Wc + (size_t)250 * NH);
        float4 t3 = *(const float4*)(Wc + (size_t)251 * NH);
        PROJ_PHASE(t0, t1, t2, t3, 248);
        t0 = *(const float4*)(Wc + (size_t)252 * NH);
        t1 = *(const float4*)(Wc + (size_t)253 * NH);
        t2 = *(const float4*)(Wc + (size_t)254 * NH);
        t3 = *(const float4*)(Wc + (size_t)255 * NH);
        PROJ_PHASE(t0, t1, t2, t3, 252);
    }
#undef PROJ_PHASE

    const float c = SCALE2;
    float4 o;
    o.x=a0.x*c; o.y=a0.y*c; o.z=a0.z*c; o.w=a0.w*c;
    *(float4*)(dst + (size_t)(g +  0) * NH + h4 * 4) = o;
    o.x=a1.x*c; o.y=a1.y*c; o.z=a1.z*c; o.w=a1.w*c;
    *(float4*)(dst + (size_t)(g +  8) * NH + h4 * 4) = o;
    o.x=a2.x*c; o.y=a2.y*c; o.z=a2.z*c; o.w=a2.w*c;
    *(float4*)(dst + (size_t)(g + 16) * NH + h4 * 4) = o;
    o.x=a3.x*c; o.y=a3.y*c; o.z=a3.z*c; o.w=a3.w*c;
    *(float4*)(dst + (size_t)(g + 24) * NH + h4 * 4) = o;
}

// ---------------------------------------------------------------
// K2: pT[b,k,q] = exp(scores) (masked -> 0), transposed layout.
// 4-way sigmoid combine: 5 trans + 14 VALU per 4 elems.
// Early-exit for fully-masked 64-key tiles (~22% of blocks).
// ---------------------------------------------------------------
__global__ __launch_bounds__(256, 4) void scores_kernel(
    const float* __restrict__ qp, const float* __restrict__ kp,
    const float* __restrict__ Ws, const int* __restrict__ valid_len,
    float* __restrict__ pT)
{
    __shared__ __align__(16) float kp_s[64 * 128];
    __shared__ __align__(16) float qp_s[8 * 128];
    __shared__ __align__(16) float ws_s[128];

    const int kt  = blockIdx.x;   // 0..15
    const int qt  = blockIdx.y;   // 0..7
    const int b   = blockIdx.z;   // 0..15
    const int tid = threadIdx.x;
    const int lane = tid & 63;
    const int w    = tid >> 6;
    const int kg   = kt * 64 + lane;
    const int vl   = valid_len[b];

    if (kt * 64 + 63 < vl) {      // whole tile masked
        pT[((size_t)b * NK + kg) * NQ + qt * 8 + w]     = 0.0f;
        pT[((size_t)b * NK + kg) * NQ + qt * 8 + w + 4] = 0.0f;
        return;
    }

    // stage kp tile: 64 rows x 128 cols = 2048 float4, swizzled
    const float4* ksrc = (const float4*)(kp + (size_t)(b * NK + kt * 64) * NH);
#pragma unroll
    for (int i = 0; i < 8; ++i) {
        const int idx = tid + i * 256;          // 0..2047
        const int row = idx >> 5, c = idx & 31;
        const float4 v = ksrc[idx];
        *(float4*)(kp_s + row * 128 + 4 * (c ^ (row & 7))) = v;
    }
    ((float4*)qp_s)[tid & 255] = ((const float4*)(qp + (size_t)(b * NQ + qt * 8) * NH))[tid & 255];
    if (tid < 32) {
        float4 t = ((const float4*)Ws)[tid];
        t.x *= -2.f; t.y *= -2.f; t.z *= -2.f; t.w *= -2.f;
        ((float4*)ws_s)[tid] = t;
    }
    __syncthreads();

    // sumWs via butterfly (ws_s holds -2*ws)
    float sw = ws_s[lane] + ws_s[lane + 64];
#pragma unroll
    for (int off = 32; off; off >>= 1) sw += __shfl_xor(sw, off);
    const float sW = -0.5f * sw;

    const float* qa = qp_s + w * 128;
    const float* qb = qp_s + (w + 4) * 128;
    const float* kr = kp_s + lane * 128;
    const int sw_x = lane & 7;

    float s0 = 0.f, s1 = 0.f;
#pragma unroll 4
    for (int c = 0; c < 32; ++c) {
        const float4 kv = *(const float4*)(kr + 4 * (c ^ sw_x));
        const float4 va = *(const float4*)(qa + 4 * c);
        const float4 vb = *(const float4*)(qb + 4 * c);
        const float4 wv = *(const float4*)(ws_s + 4 * c);
        {   // row a: 4 exp2 + 1 rcp
            const float u0 = 1.0f + exp2_fast(va.x + kv.x);
            const float u1 = 1.0f + exp2_fast(va.y + kv.y);
            const float u2 = 1.0f + exp2_fast(va.z + kv.z);
            const float u3 = 1.0f + exp2_fast(va.w + kv.w);
            const float d01 = u0 * u1, d23 = u2 * u3;
            const float n01 = fmaf(wv.y, u0, wv.x * u1);
            const float n23 = fmaf(wv.w, u2, wv.z * u3);
            const float n   = fmaf(n23, d01, n01 * d23);
            s0 = fmaf(n, rcp_fast(d01 * d23), s0);
        }
        {   // row b
            const float u0 = 1.0f + exp2_fast(vb.x + kv.x);
            const float u1 = 1.0f + exp2_fast(vb.y + kv.y);
            const float u2 = 1.0f + exp2_fast(vb.z + kv.z);
            const float u3 = 1.0f + exp2_fast(vb.w + kv.w);
            const float d01 = u0 * u1, d23 = u2 * u3;
            const float n01 = fmaf(wv.y, u0, wv.x * u1);
            const float n23 = fmaf(wv.w, u2, wv.z * u3);
            const float n   = fmaf(n23, d01, n01 * d23);
            s1 = fmaf(n, rcp_fast(d01 * d23), s1);
        }
    }

    const float p0 = (kg >= vl) ? exp2_fast((sW + s0) * L2E) : 0.0f;
    const float p1 = (kg >= vl) ? exp2_fast((sW + s1) * L2E) : 0.0f;
    pT[((size_t)b * NK + kg) * NQ + qt * 8 + w]     = p0;
    pT[((size_t)b * NK + kg) * NQ + qt * 8 + w + 4] = p1;
}

// ---------------------------------------------------------------
// K3: partial PV + partial z. 64-key tiles, grid 512.
// Early-exit ~22% of tiles.
// ---------------------------------------------------------------
__global__ __launch_bounds__(256) void pv_kernel(
    const float* __restrict__ pT, const float* __restrict__ values,
    const int* __restrict__ valid_len,
    float* __restrict__ part, float* __restrict__ zpart)
{
    __shared__ __align__(16) float a_s[64][36];
    __shared__ float zp_s[4][32];
    const int kt  = blockIdx.x;   // 0..15
    const int qh  = blockIdx.y;   // 0..1
    const int b   = blockIdx.z;   // 0..15
    const int tid = threadIdx.x;

    const int vl = valid_len[b];
    if (kt * 64 + 63 < vl) {      // whole tile masked -> partials zero
        if (tid < 32) zpart[((size_t)kt * NB + b) * NQ + qh * 32 + tid] = 0.f;
#pragma unroll
        for (int q = 0; q < 32; ++q)
            part[(((size_t)kt * NB + b) * NQ + qh * 32 + q) * VS + tid] = 0.f;
        return;
    }

    // stage a-tile: 64 k x 32 q (512 float4, 2 per thread)
    {
        const int q4 = (tid & 7) * 4;
        const int k0 = tid >> 3;          // 0..31
#pragma unroll
        for (int i = 0; i < 2; ++i) {
            const int k = k0 + 32 * i;
            const float4 v = *(const float4*)(
                pT + ((size_t)b * NK + kt * 64 + k) * NQ + qh * 32 + q4);
            *(float4*)(&a_s[k][q4]) = v;
        }
    }
    __syncthreads();

    // partial z: wave w sums k in [16w, 16w+16), q' = lane&31
    {
        const int lane = tid & 63;
        const int w    = tid >> 6;
        const int qq   = lane & 31;
        float z = 0.f;
#pragma unroll
        for (int i = 0; i < 16; ++i) z += a_s[w * 16 + i][qq];
        if (lane < 32) zp_s[w][qq] = z;
    }
    __syncthreads();
    if (tid < 32) {
        const float zf = zp_s[0][tid] + zp_s[1][tid] + zp_s[2][tid] + zp_s[3][tid];
        zpart[((size_t)kt * NB + b) * NQ + qh * 32 + tid] = zf;
    }

    // main: thread = vcol, 32 q accumulators, 64-k loop
    float acc[32];
#pragma unroll
    for (int i = 0; i < 32; ++i) acc[i] = 0.f;

    const float* vb = values + ((size_t)b * NK + kt * 64) * VS + tid;
#pragma unroll 4
    for (int k = 0; k < 64; ++k) {
        const float v = vb[(size_t)k * VS];
#pragma unroll
        for (int j = 0; j < 8; ++j) {
            const float4 a = *(const float4*)(&a_s[k][4 * j]);
            acc[4*j+0] = fmaf(a.x, v, acc[4*j+0]);
            acc[4*j+1] = fmaf(a.y, v, acc[4*j+1]);
            acc[4*j+2] = fmaf(a.z, v, acc[4*j+2]);
            acc[4*j+3] = fmaf(a.w, v, acc[4*j+3]);
        }
    }
#pragma unroll
    for (int q = 0; q < 32; ++q)
        part[(((size_t)kt * NB + b) * NQ + qh * 32 + q) * VS + tid] = acc[q];
}

// ---------------------------------------------------------------
// K4: out = (sum_kt part) / (sum_kt zpart). One block per (b,q) row.
// ---------------------------------------------------------------
__global__ __launch_bounds__(256) void finish_kernel(
    const float* __restrict__ part, const float* __restrict__ zpart,
    float* __restrict__ out)
{
    const int r   = blockIdx.x;   // b*64+q
    const int tid = threadIdx.x;
    const int b = r >> 6, q = r & 63;
    float z = 0.f, s = 0.f;
#pragma unroll
    for (int kt = 0; kt < KT; ++kt) {
        z += zpart[((size_t)kt * NB + b) * NQ + q];
        s += part[(((size_t)kt * NB + b) * NQ + q) * VS + tid];
    }
    out[(size_t)r * VS + tid] = s / z;
}

// ---------------------------------------------------------------
extern "C" void kernel_launch(void* const* d_in, const int* in_sizes, int n_in,
                              void* d_out, int out_size, void* d_ws, size_t ws_size,
                              hipStream_t stream)
{
    (void)in_sizes; (void)n_in; (void)out_size; (void)ws_size;
    const float* queries = (const float*)d_in[0];
    const float* keys    = (const float*)d_in[1];
    const float* values  = (const float*)d_in[2];
    const int*   vlen    = (const int*)d_in[3];
    const float* Wq      = (const float*)d_in[4];
    const float* Wk      = (const float*)d_in[5];
    const float* Ws      = (const float*)d_in[6];
    float* out = (float*)d_out;

    // workspace layout (floats), no overlays: ~30 MB total
    float* qp    = (float*)d_ws;           // 131072
    float* kp    = qp + 131072;            // 2097152
    float* pT    = kp + 2097152;           // 1048576
    float* zpart = pT + 1048576;           // 16384 (KT*NB*NQ)
    float* part  = zpart + 16384;          // 4194304 (KT*NB*NQ*VS)

    proj_kernel<<<544, 256, 0, stream>>>(queries, keys, Wq, Wk, qp, kp);
    scores_kernel<<<dim3(16, 8, 16), 256, 0, stream>>>(qp, kp, Ws, vlen, pT);
    pv_kernel<<<dim3(KT, 2, 16), 256, 0, stream>>>(pT, values, vlen, part, zpart);
    finish_kernel<<<1024, 256, 0, stream>>>(part, zpart, out);
}